// Round 10
// baseline (1356.784 us; speedup 1.0000x reference)
//
#include <hip/hip_runtime.h>
#include <cstddef>

static constexpr int   NN      = 2048;
static constexpr int   TPB_B   = 256;   // build_cost block
static constexpr int   TPB     = 512;   // main kernel block (8 waves)
static constexpr int   NWB     = TPB / 64;          // 8 waves/block
static constexpr int   NB      = 256;               // main grid blocks (1/CU)
static constexpr int   MAX_IT  = 100;
static constexpr float EPS     = 0.1f;
static constexpr float INV_EPS = 10.0f;
// logf(1/2048 + 1e-8)
static constexpr float LOG_AB  = -7.6245985063594f;
static constexpr float THRESH  = 0.1f;

#define ALOAD(p)     __hip_atomic_load((p),  __ATOMIC_RELAXED, __HIP_MEMORY_SCOPE_AGENT)
#define ASTORE(p, x) __hip_atomic_store((p), (x), __ATOMIC_RELAXED, __HIP_MEMORY_SCOPE_AGENT)

typedef unsigned long long u64;

// ---------------------------------------------------------------------------
// Cost matrix build + signal-region zeroing. C[i][j] = sum_d (x[i,d]-y[j,d])^2.
// (harness poisons ws with 0xAA before every call; 0xAAAA.. would falsely
//  validate epoch checks -> must re-zero every launch. Kernel-end implicit
//  L2 writeback makes these plain stores visible to main's bypass loads.)
// ---------------------------------------------------------------------------
__global__ __launch_bounds__(TPB_B)
void build_cost(const float* __restrict__ x, const float* __restrict__ y,
                float* __restrict__ C, float* __restrict__ CT,
                unsigned* __restrict__ zz, int zcount,
                int c_aligned, int use_ct)
{
    __shared__ float xs[64][65];
    __shared__ float ys[64][65];
    const int t  = threadIdx.x;
    const int bi = blockIdx.y, bj = blockIdx.x;

    if (bi == 0) {                       // 32 blocks zero the region in parallel
        int per = (zcount + 31) / 32;
        int lo = bj * per;
        int hi = lo + per; if (hi > zcount) hi = zcount;
        for (int idx = lo + t; idx < hi; idx += TPB_B) zz[idx] = 0u;
    }

#pragma unroll
    for (int k = 0; k < 16; ++k) {
        int idx = t + TPB_B * k;
        int r = idx >> 6, c = idx & 63;
        xs[r][c] = x[(size_t)(bi * 64 + r) * 64 + c];
        ys[r][c] = y[(size_t)(bj * 64 + r) * 64 + c];
    }
    __syncthreads();

    const int ti0 = (t >> 4) * 4;
    const int tj0 = (t & 15) * 4;
    float acc[4][4] = {};
#pragma unroll 8
    for (int d = 0; d < 64; ++d) {
        float xv[4], yv[4];
#pragma unroll
        for (int k = 0; k < 4; ++k) xv[k] = xs[ti0 + k][d];
#pragma unroll
        for (int l = 0; l < 4; ++l) yv[l] = ys[tj0 + l][d];
#pragma unroll
        for (int k = 0; k < 4; ++k)
#pragma unroll
            for (int l = 0; l < 4; ++l) {
                float df = xv[k] - yv[l];
                acc[k][l] = fmaf(df, df, acc[k][l]);
            }
    }

#pragma unroll
    for (int k = 0; k < 4; ++k) {
        size_t off = (size_t)(bi * 64 + ti0 + k) * NN + bj * 64 + tj0;
        if (c_aligned) {
            *(float4*)(C + off) = make_float4(acc[k][0], acc[k][1], acc[k][2], acc[k][3]);
        } else {
            C[off + 0] = acc[k][0]; C[off + 1] = acc[k][1];
            C[off + 2] = acc[k][2]; C[off + 3] = acc[k][3];
        }
    }
    if (use_ct) {
#pragma unroll
        for (int l = 0; l < 4; ++l) {
            size_t off = (size_t)(bj * 64 + tj0 + l) * NN + bi * 64 + ti0;
            *(float4*)(CT + off) = make_float4(acc[0][l], acc[1][l], acc[2][l], acc[3][l]);
        }
    }
}

// ---------------------------------------------------------------------------
// Helpers
// ---------------------------------------------------------------------------
__device__ __forceinline__ void load_row32(const float* row, int lane,
                                           int aligned, float c[32])
{
    if (aligned) {
        const float4* r4 = (const float4*)row;
#pragma unroll
        for (int k = 0; k < 8; ++k) {
            float4 A = r4[lane + 64 * k];
            c[4*k+0] = A.x; c[4*k+1] = A.y; c[4*k+2] = A.z; c[4*k+3] = A.w;
        }
    } else {
#pragma unroll
        for (int k = 0; k < 8; ++k) {
            const float* p = row + 4 * (lane + 64 * k);
            c[4*k+0] = p[0]; c[4*k+1] = p[1]; c[4*k+2] = p[2]; c[4*k+3] = p[3];
        }
    }
}

__device__ __forceinline__ void lds_row32(const float* sv, int lane, float b[32])
{
    const float4* s4 = (const float4*)sv;
#pragma unroll
    for (int k = 0; k < 8; ++k) {
        float4 A = s4[lane + 64 * k];
        b[4*k+0] = A.x; b[4*k+1] = A.y; b[4*k+2] = A.z; b[4*k+3] = A.w;
    }
}

// wave-level lse of (b-c)*INV_EPS over 2048 elems; result on ALL lanes.
__device__ __forceinline__ float wave_lse(const float c[32], const float b[32])
{
    float M = b[0] - c[0];
#pragma unroll
    for (int k = 1; k < 32; ++k) M = fmaxf(M, b[k] - c[k]);
#pragma unroll
    for (int off = 1; off < 64; off <<= 1) M = fmaxf(M, __shfl_xor(M, off));
    float Ms = M * INV_EPS;
    float s = 0.0f;
#pragma unroll
    for (int k = 0; k < 32; ++k) s += __expf(fmaf(b[k] - c[k], INV_EPS, -Ms));
#pragma unroll
    for (int off = 1; off < 64; off <<= 1) s += __shfl_xor(s, off);
    return Ms + __logf(s);
}

// ---------------------------------------------------------------------------
// Poll the (single, shared) self-validating array until all 2048 {epoch|f32}
// entries reach epoch ep. Coalesced pattern: thread t owns entries
// {t, t+512, t+1024, t+1536} -> every load is 64-lane contiguous.
// Validation is ONE u64 compare: d >= (ep<<32)  <=>  epoch(d) >= ep
// (epoch monotone; value bits can't flip the inequality).
// Deposits values into LDS dst and leaves per-wave sum|new-old| in pdw[w]
// (fixed order -> bit-identical in every block -> uniform break).
// Caller must __syncthreads() before dst is consumed.
// ---------------------------------------------------------------------------
__device__ __forceinline__ void poll2(const u64* __restrict__ arr, unsigned ep,
                                      float* dst, float* pdw, int t)
{
    const int lane = t & 63, w = t >> 6;
    const u64 thr = (u64)ep << 32;
    u64 d0, d1, d2, d3;
    for (;;) {
        d0 = ALOAD(arr + t);
        d1 = ALOAD(arr + t + 512);
        d2 = ALOAD(arr + t + 1024);
        d3 = ALOAD(arr + t + 1536);
        if ((d0 >= thr) & (d1 >= thr) & (d2 >= thr) & (d3 >= thr)) break;
    }
    float n0 = __uint_as_float((unsigned)d0);
    float n1 = __uint_as_float((unsigned)d1);
    float n2 = __uint_as_float((unsigned)d2);
    float n3 = __uint_as_float((unsigned)d3);
    float du = fabsf(n0 - dst[t])        + fabsf(n1 - dst[t + 512])
             + fabsf(n2 - dst[t + 1024]) + fabsf(n3 - dst[t + 1536]);
    dst[t] = n0; dst[t + 512] = n1; dst[t + 1024] = n2; dst[t + 1536] = n3;
#pragma unroll
    for (int off = 1; off < 64; off <<= 1) du += __shfl_xor(du, off);
    if (lane == 0) pdw[w] = du;
}

// ---------------------------------------------------------------------------
// Main cooperative kernel. 256 blocks x 512 thr; wave w of block b owns
// row/col i = b*8+w. C row + CT col register/L1-resident (loop-invariant,
// no fences ever -> per-XCD L2 stays warm). Cross-block exchange: ONE shared
// self-validating array per direction; post = one 8B bypass store by the
// owning wave's lane 0, the instant its LSE finishes (no staging, no drain,
// no flag, no aggregation hop). Detection IS the data fetch (R7 lesson);
// single array, no replication (R9 lesson: fan-out posts = HBM write storm);
// broadcast-shaped polling only (R6 lesson). Diff is computed locally from
// LDS old/new (zero extra RTTs). One __syncthreads per half-iteration.
// Reuse safety: owner posts epoch e+1 to valA[i] only after polling all of
// valB(e), which requires every block to have posted valB(e), which requires
// they finished reading valA(e)[i] -> no overwrite race; during any block's
// e-poll no entry can exceed e -> deposit reads exactly the e values.
// Cm may alias out+1 (crow/ccol resident before any overwrite).
// ---------------------------------------------------------------------------
__global__ __launch_bounds__(TPB)
void sinkhorn_main(const float* Cm, const float* __restrict__ CT,
                   u64* __restrict__ valA, u64* __restrict__ valB,
                   u64* __restrict__ costb,
                   float* out, int c_aligned, int use_ct)
{
    __shared__ float su[2048];     // current u vector
    __shared__ float svv[2048];    // current v vector
    __shared__ float sdu[NWB];     // per-wave diff partials (row)
    __shared__ float sdv[NWB];     // per-wave diff partials (col)
    __shared__ float sred4[4];
    const int t = threadIdx.x, lane = t & 63, w = t >> 6, b = blockIdx.x;
    const int i = b * NWB + w;

    // loop-invariant C row / CT col -> registers (spill-to-L1 acceptable)
    float crow[32], ccol[32];
    load_row32(Cm + (size_t)i * NN, lane, c_aligned, crow);
    if (use_ct) {
        load_row32(CT + (size_t)i * NN, lane, 1, ccol);
    } else {
#pragma unroll
        for (int k = 0; k < 8; ++k)
#pragma unroll
            for (int kk = 0; kk < 4; ++kk)
                ccol[4*k+kk] = Cm[(size_t)(4 * (lane + 64 * k) + kk) * NN + i];
    }

    for (int k = t; k < 2048; k += TPB) { su[k] = 0.0f; svv[k] = 0.0f; }
    __syncthreads();

    float u_keep = 0.0f;
    float b32[32];

    for (int it = 0; it < MAX_IT; ++it) {
        const unsigned ep = (unsigned)(it + 1);

        // ---- deferred convergence check (diffs of iteration it-1; all local,
        //      every thread computes the same fixed-order sum -> uniform)
        if (it >= 1) {
            float s = 0.0f;
#pragma unroll
            for (int k = 0; k < NWB; ++k) s += sdu[k] + sdv[k];
            if (s < THRESH) break;    // state: su=u(it), svv=v(it), u_keep=u(it)
        }

        // ---- row: u(ep)_i from svv = v(it); post immediately, then poll
        lds_row32(svv, lane, b32);
        float lse   = wave_lse(crow, b32);
        float u_new = EPS * (LOG_AB - lse);              // wave-uniform
        if (lane == 0)
            ASTORE(&valA[i], ((u64)ep << 32) | __float_as_uint(u_new));
        poll2(valA, ep, su, sdu, t);
        u_keep = u_new;
        __syncthreads();

        // ---- col: v(ep)_j from su = u(ep); post immediately, then poll
        lds_row32(su, lane, b32);
        lse = wave_lse(ccol, b32);
        float v_new = EPS * (LOG_AB - lse);
        if (lane == 0)
            ASTORE(&valB[i], ((u64)ep << 32) | __float_as_uint(v_new));
        poll2(valB, ep, svv, sdv, t);
        __syncthreads();
    }

    // ---- epilogue: pi = exp((u_i + v_j - C_ij)/eps), cost = sum(pi*C)
    float cpart = 0.0f;
    {
        lds_row32(svv, lane, b32);         // final v
        const float ui = u_keep;           // own row's final u (wave-uniform)
        float* orow = out + 1 + (size_t)i * NN;
#pragma unroll
        for (int k = 0; k < 8; ++k) {
#pragma unroll
            for (int kk = 0; kk < 4; ++kk) {
                float cc = crow[4*k+kk];
                float p  = __expf((ui + b32[4*k+kk] - cc) * INV_EPS);
                cpart = fmaf(p, cc, cpart);
                orow[4 * (lane + 64 * k) + kk] = p;  // crow in regs: alias-safe
            }
        }
    }
#pragma unroll
    for (int off = 1; off < 64; off <<= 1) cpart += __shfl_xor(cpart, off);
    if (lane == 0) sdu[w] = cpart;
    __syncthreads();
    if (t == 0) {
        float pc = 0.0f;
#pragma unroll
        for (int k = 0; k < NWB; ++k) pc += sdu[k];
        ASTORE(&costb[b], (1ull << 32) | __float_as_uint(pc));
    }
    if (b == 0) {                          // block 0 gathers the cost total
        if (t < 256) {
            u64 h;
            for (;;) { h = ALOAD(&costb[t]); if (h >= (1ull << 32)) break; }
            float pc = __uint_as_float((unsigned)h);
#pragma unroll
            for (int off = 1; off < 64; off <<= 1) pc += __shfl_xor(pc, off);
            if (lane == 0) sred4[w] = pc;
        }
        __syncthreads();
        if (t == 0) out[0] = sred4[0] + sred4[1] + sred4[2] + sred4[3];
    }
}

// ---------------------------------------------------------------------------
extern "C" void kernel_launch(void* const* d_in, const int* in_sizes, int n_in,
                              void* d_out, int out_size, void* d_ws, size_t ws_size,
                              hipStream_t stream)
{
    (void)in_sizes; (void)n_in; (void)out_size;
    const float* x = (const float*)d_in[0];
    const float* y = (const float*)d_in[1];
    float* out = (float*)d_out;
    char*  ws  = (char*)d_ws;

    const size_t CB = (size_t)NN * NN * sizeof(float);   // 16 MiB
    const size_t ZB = (2048 + 2048 + 256) * sizeof(u64); // 34 KiB signals

    float *Cm, *CT; char* zz;
    int c_aligned, use_ct;
    if (ws_size >= 2 * CB + ZB) {             // preferred: C, CT, signals in ws
        Cm = (float*)ws; CT = (float*)(ws + CB); zz = ws + 2 * CB;
        c_aligned = 1; use_ct = 1;
    } else if (ws_size >= CB + ZB) {          // C in out+1, CT in ws
        Cm = out + 1; CT = (float*)ws; zz = ws + CB;
        c_aligned = 0; use_ct = 1;
    } else {                                  // C in out+1, no CT (strided)
        Cm = out + 1; CT = nullptr; zz = ws;
        c_aligned = 0; use_ct = 0;
    }
    // u64 layout in zz: valA[0,2048) valB[2048,4096) costb[4096,4352)
    u64* valA  = (u64*)zz;
    u64* valB  = valA + 2048;
    u64* costb = valB + 2048;
    int  zcount = 4352 * 2;                   // u32 elements to zero

    hipLaunchKernelGGL(build_cost, dim3(32, 32), dim3(TPB_B), 0, stream,
                       x, y, Cm, CT, (unsigned*)zz, zcount, c_aligned, use_ct);

    const float* Cmc = Cm;
    const float* CTc = CT;
    void* args[] = { (void*)&Cmc, (void*)&CTc, (void*)&valA, (void*)&valB,
                     (void*)&costb, (void*)&out, (void*)&c_aligned,
                     (void*)&use_ct };
    hipLaunchCooperativeKernel((void*)sinkhorn_main, dim3(NB), dim3(TPB),
                               args, 0, stream);
}

// Round 11
// 966.909 us; speedup vs baseline: 1.4032x; 1.4032x over previous
//
#include <hip/hip_runtime.h>
#include <cstddef>

static constexpr int   NN      = 2048;
static constexpr int   TPB_B   = 256;   // build_cost block
static constexpr int   TPB     = 512;   // main kernel block (8 waves)
static constexpr int   NWB     = TPB / 64;          // 8 waves/block
static constexpr int   NB      = 256;               // main grid blocks (1/CU)
static constexpr int   MAX_IT  = 100;
static constexpr float EPS     = 0.1f;
static constexpr float INV_EPS = 10.0f;
// logf(1/2048 + 1e-8)
static constexpr float LOG_AB  = -7.6245985063594f;
static constexpr float THRESH  = 0.1f;

#define ALOAD(p)     __hip_atomic_load((p),  __ATOMIC_RELAXED, __HIP_MEMORY_SCOPE_AGENT)
#define ASTORE(p, x) __hip_atomic_store((p), (x), __ATOMIC_RELAXED, __HIP_MEMORY_SCOPE_AGENT)

typedef unsigned long long u64;

// ---------------------------------------------------------------------------
// Cost matrix build + signal-region zeroing. C[i][j] = sum_d (x[i,d]-y[j,d])^2.
// (harness poisons ws with 0xAA before every call -> re-zero signals every
//  launch; kernel-end L2 writeback makes plain stores visible to bypass loads)
// ---------------------------------------------------------------------------
__global__ __launch_bounds__(TPB_B)
void build_cost(const float* __restrict__ x, const float* __restrict__ y,
                float* __restrict__ C, float* __restrict__ CT,
                unsigned* __restrict__ zz, int zcount,
                int c_aligned, int use_ct)
{
    __shared__ float xs[64][65];
    __shared__ float ys[64][65];
    const int t  = threadIdx.x;
    const int bi = blockIdx.y, bj = blockIdx.x;

    if (bi == 0) {                       // 32 blocks zero the region in parallel
        int per = (zcount + 31) / 32;
        int lo = bj * per;
        int hi = lo + per; if (hi > zcount) hi = zcount;
        for (int idx = lo + t; idx < hi; idx += TPB_B) zz[idx] = 0u;
    }

#pragma unroll
    for (int k = 0; k < 16; ++k) {
        int idx = t + TPB_B * k;
        int r = idx >> 6, c = idx & 63;
        xs[r][c] = x[(size_t)(bi * 64 + r) * 64 + c];
        ys[r][c] = y[(size_t)(bj * 64 + r) * 64 + c];
    }
    __syncthreads();

    const int ti0 = (t >> 4) * 4;
    const int tj0 = (t & 15) * 4;
    float acc[4][4] = {};
#pragma unroll 8
    for (int d = 0; d < 64; ++d) {
        float xv[4], yv[4];
#pragma unroll
        for (int k = 0; k < 4; ++k) xv[k] = xs[ti0 + k][d];
#pragma unroll
        for (int l = 0; l < 4; ++l) yv[l] = ys[tj0 + l][d];
#pragma unroll
        for (int k = 0; k < 4; ++k)
#pragma unroll
            for (int l = 0; l < 4; ++l) {
                float df = xv[k] - yv[l];
                acc[k][l] = fmaf(df, df, acc[k][l]);
            }
    }

#pragma unroll
    for (int k = 0; k < 4; ++k) {
        size_t off = (size_t)(bi * 64 + ti0 + k) * NN + bj * 64 + tj0;
        if (c_aligned) {
            *(float4*)(C + off) = make_float4(acc[k][0], acc[k][1], acc[k][2], acc[k][3]);
        } else {
            C[off + 0] = acc[k][0]; C[off + 1] = acc[k][1];
            C[off + 2] = acc[k][2]; C[off + 3] = acc[k][3];
        }
    }
    if (use_ct) {
#pragma unroll
        for (int l = 0; l < 4; ++l) {
            size_t off = (size_t)(bj * 64 + tj0 + l) * NN + bi * 64 + ti0;
            *(float4*)(CT + off) = make_float4(acc[0][l], acc[1][l], acc[2][l], acc[3][l]);
        }
    }
}

// ---------------------------------------------------------------------------
// Helpers
// ---------------------------------------------------------------------------
__device__ __forceinline__ void load_row32(const float* row, int lane,
                                           int aligned, float c[32])
{
    if (aligned) {
        const float4* r4 = (const float4*)row;
#pragma unroll
        for (int k = 0; k < 8; ++k) {
            float4 A = r4[lane + 64 * k];
            c[4*k+0] = A.x; c[4*k+1] = A.y; c[4*k+2] = A.z; c[4*k+3] = A.w;
        }
    } else {
#pragma unroll
        for (int k = 0; k < 8; ++k) {
            const float* p = row + 4 * (lane + 64 * k);
            c[4*k+0] = p[0]; c[4*k+1] = p[1]; c[4*k+2] = p[2]; c[4*k+3] = p[3];
        }
    }
}

__device__ __forceinline__ void lds_row32(const float* sv, int lane, float b[32])
{
    const float4* s4 = (const float4*)sv;
#pragma unroll
    for (int k = 0; k < 8; ++k) {
        float4 A = s4[lane + 64 * k];
        b[4*k+0] = A.x; b[4*k+1] = A.y; b[4*k+2] = A.z; b[4*k+3] = A.w;
    }
}

// wave-level lse of (b-c)*INV_EPS over 2048 elems; result on ALL lanes.
__device__ __forceinline__ float wave_lse(const float c[32], const float b[32])
{
    float M = b[0] - c[0];
#pragma unroll
    for (int k = 1; k < 32; ++k) M = fmaxf(M, b[k] - c[k]);
#pragma unroll
    for (int off = 1; off < 64; off <<= 1) M = fmaxf(M, __shfl_xor(M, off));
    float Ms = M * INV_EPS;
    float s = 0.0f;
#pragma unroll
    for (int k = 0; k < 32; ++k) s += __expf(fmaf(b[k] - c[k], INV_EPS, -Ms));
#pragma unroll
    for (int off = 1; off < 64; off <<= 1) s += __shfl_xor(s, off);
    return Ms + __logf(s);
}

// ---------------------------------------------------------------------------
// Poll the single shared self-validating array until all 2048 {epoch|f32}
// entries reach epoch ep (proven R8 pattern: thread t owns entries 4t..4t+3).
// Validation: one u64 compare (d >= ep<<32 <=> epoch >= ep, epoch monotone).
// Deposits values into LDS dst[4t..4t+3] and leaves per-wave sum|new-old|
// in pdw[w] (fixed order -> bit-identical in every block -> uniform break).
// Caller must __syncthreads() before dst/pdw are consumed.
// ---------------------------------------------------------------------------
__device__ __forceinline__ void poll_dep(const u64* __restrict__ arr, unsigned ep,
                                         float* dst, float* pdw, int t)
{
    const int lane = t & 63, w = t >> 6;
    const int base = 4 * t;
    const u64 thr = (u64)ep << 32;
    u64 d0, d1, d2, d3;
    for (;;) {
        d0 = ALOAD(arr + base + 0); d1 = ALOAD(arr + base + 1);
        d2 = ALOAD(arr + base + 2); d3 = ALOAD(arr + base + 3);
        if ((d0 >= thr) & (d1 >= thr) & (d2 >= thr) & (d3 >= thr)) break;
    }
    float n0 = __uint_as_float((unsigned)d0);
    float n1 = __uint_as_float((unsigned)d1);
    float n2 = __uint_as_float((unsigned)d2);
    float n3 = __uint_as_float((unsigned)d3);
    float4 o = ((const float4*)dst)[t];
    float du = fabsf(n0 - o.x) + fabsf(n1 - o.y)
             + fabsf(n2 - o.z) + fabsf(n3 - o.w);
    ((float4*)dst)[t] = make_float4(n0, n1, n2, n3);
#pragma unroll
    for (int off = 1; off < 64; off <<= 1) du += __shfl_xor(du, off);
    if (lane == 0) pdw[w] = du;
}

// ---------------------------------------------------------------------------
// Main cooperative kernel. 256 blocks x 512 thr; wave w of block b owns
// row/col i = b*8+w. C row + CT col register-resident (loop-invariant; no
// fences ever -> per-XCD L2 stays warm). Cross-block exchange: ONE shared
// self-validating u64 array per direction. Posts are STAGED: after a block
// sync, lanes 0-7 of wave 0 store the block's 8 values as one coalesced
// 64B wave-store (minimum signal-store op count — R9/R10 lesson: scattered
// or per-wave bypass stores cost a memory-side partial-line op each).
// Detection IS the data fetch (R7); single array (R9); broadcast-shaped
// polls (R6). Convergence diff computed LOCALLY from LDS old/new -> the
// rot-poll RTTs of the 827us kernel are deleted outright.
// Cm may alias out+1 (crow/ccol resident before any overwrite).
// ---------------------------------------------------------------------------
__global__ __launch_bounds__(TPB)
void sinkhorn_main(const float* Cm, const float* __restrict__ CT,
                   u64* __restrict__ valA, u64* __restrict__ valB,
                   u64* __restrict__ costb,
                   float* out, int c_aligned, int use_ct)
{
    __shared__ float su[2048];     // current u vector
    __shared__ float svv[2048];    // current v vector
    __shared__ float swave[NWB];   // staging for the block's 8 posts
    __shared__ float sdu[NWB];     // per-wave diff partials (row)
    __shared__ float sdv[NWB];     // per-wave diff partials (col)
    __shared__ float sred4[4];
    const int t = threadIdx.x, lane = t & 63, w = t >> 6, b = blockIdx.x;
    const int i = b * NWB + w;

    // loop-invariant C row / CT col -> registers
    float crow[32], ccol[32];
    load_row32(Cm + (size_t)i * NN, lane, c_aligned, crow);
    if (use_ct) {
        load_row32(CT + (size_t)i * NN, lane, 1, ccol);
    } else {
#pragma unroll
        for (int k = 0; k < 8; ++k)
#pragma unroll
            for (int kk = 0; kk < 4; ++kk)
                ccol[4*k+kk] = Cm[(size_t)(4 * (lane + 64 * k) + kk) * NN + i];
    }

    for (int k = t; k < 2048; k += TPB) { su[k] = 0.0f; svv[k] = 0.0f; }
    __syncthreads();

    float u_keep = 0.0f;
    float b32[32];

    for (int it = 0; it < MAX_IT; ++it) {
        const unsigned ep = (unsigned)(it + 1);

        // ---- deferred convergence check: diffs of iteration it-1, all in
        //      LDS (zero RTT). Fixed-order sum, identical in every block.
        if (it >= 1) {
            float s = 0.0f;
#pragma unroll
            for (int k = 0; k < NWB; ++k) s += sdu[k] + sdv[k];
            if (s < THRESH) break;   // state: su=u(it), svv=v(it), u_keep=u(it)
        }

        // ---- row: u(ep)_i from svv = v(it)
        lds_row32(svv, lane, b32);
        float lse   = wave_lse(crow, b32);
        float u_new = EPS * (LOG_AB - lse);              // wave-uniform
        if (lane == 0) swave[w] = u_new;
        __syncthreads();
        if (t < NWB)                                     // ONE 64B wave-store
            ASTORE(&valA[b * NWB + t],
                   ((u64)ep << 32) | __float_as_uint(swave[t]));
        poll_dep(valA, ep, su, sdu, t);
        u_keep = u_new;
        __syncthreads();

        // ---- col: v(ep)_j from su = u(ep)
        lds_row32(su, lane, b32);
        lse = wave_lse(ccol, b32);
        float v_new = EPS * (LOG_AB - lse);
        if (lane == 0) swave[w] = v_new;
        __syncthreads();
        if (t < NWB)
            ASTORE(&valB[b * NWB + t],
                   ((u64)ep << 32) | __float_as_uint(swave[t]));
        poll_dep(valB, ep, svv, sdv, t);
        __syncthreads();
    }

    // ---- epilogue: pi = exp((u_i + v_j - C_ij)/eps), cost = sum(pi*C)
    float cpart = 0.0f;
    {
        lds_row32(svv, lane, b32);         // final v
        const float ui = u_keep;           // own row's final u (wave-uniform)
        float* orow = out + 1 + (size_t)i * NN;
#pragma unroll
        for (int k = 0; k < 8; ++k) {
#pragma unroll
            for (int kk = 0; kk < 4; ++kk) {
                float cc = crow[4*k+kk];
                float p  = __expf((ui + b32[4*k+kk] - cc) * INV_EPS);
                cpart = fmaf(p, cc, cpart);
                orow[4 * (lane + 64 * k) + kk] = p;  // crow in regs: alias-safe
            }
        }
    }
#pragma unroll
    for (int off = 1; off < 64; off <<= 1) cpart += __shfl_xor(cpart, off);
    if (lane == 0) sdu[w] = cpart;
    __syncthreads();
    if (t == 0) {
        float pc = 0.0f;
#pragma unroll
        for (int k = 0; k < NWB; ++k) pc += sdu[k];
        ASTORE(&costb[b], (1ull << 32) | __float_as_uint(pc));
    }
    if (b == 0) {                          // block 0 gathers the cost total
        if (t < 256) {
            u64 h;
            for (;;) { h = ALOAD(&costb[t]); if (h >= (1ull << 32)) break; }
            float pc = __uint_as_float((unsigned)h);
#pragma unroll
            for (int off = 1; off < 64; off <<= 1) pc += __shfl_xor(pc, off);
            if (lane == 0) sred4[w] = pc;
        }
        __syncthreads();
        if (t == 0) out[0] = sred4[0] + sred4[1] + sred4[2] + sred4[3];
    }
}

// ---------------------------------------------------------------------------
extern "C" void kernel_launch(void* const* d_in, const int* in_sizes, int n_in,
                              void* d_out, int out_size, void* d_ws, size_t ws_size,
                              hipStream_t stream)
{
    (void)in_sizes; (void)n_in; (void)out_size;
    const float* x = (const float*)d_in[0];
    const float* y = (const float*)d_in[1];
    float* out = (float*)d_out;
    char*  ws  = (char*)d_ws;

    const size_t CB = (size_t)NN * NN * sizeof(float);   // 16 MiB
    const size_t ZB = (2048 + 2048 + 256) * sizeof(u64); // 34 KiB signals

    float *Cm, *CT; char* zz;
    int c_aligned, use_ct;
    if (ws_size >= 2 * CB + ZB) {             // preferred: C, CT, signals in ws
        Cm = (float*)ws; CT = (float*)(ws + CB); zz = ws + 2 * CB;
        c_aligned = 1; use_ct = 1;
    } else if (ws_size >= CB + ZB) {          // C in out+1, CT in ws
        Cm = out + 1; CT = (float*)ws; zz = ws + CB;
        c_aligned = 0; use_ct = 1;
    } else {                                  // C in out+1, no CT (strided)
        Cm = out + 1; CT = nullptr; zz = ws;
        c_aligned = 0; use_ct = 0;
    }
    // u64 layout in zz: valA[0,2048) valB[2048,4096) costb[4096,4352)
    u64* valA  = (u64*)zz;
    u64* valB  = valA + 2048;
    u64* costb = valB + 2048;
    int  zcount = 4352 * 2;                   // u32 elements to zero

    hipLaunchKernelGGL(build_cost, dim3(32, 32), dim3(TPB_B), 0, stream,
                       x, y, Cm, CT, (unsigned*)zz, zcount, c_aligned, use_ct);

    const float* Cmc = Cm;
    const float* CTc = CT;
    void* args[] = { (void*)&Cmc, (void*)&CTc, (void*)&valA, (void*)&valB,
                     (void*)&costb, (void*)&out, (void*)&c_aligned,
                     (void*)&use_ct };
    hipLaunchCooperativeKernel((void*)sinkhorn_main, dim3(NB), dim3(TPB),
                               args, 0, stream);
}

// Round 12
// 736.147 us; speedup vs baseline: 1.8431x; 1.3135x over previous
//
#include <hip/hip_runtime.h>
#include <cstddef>

static constexpr int   NN      = 2048;
static constexpr int   TPB_B   = 256;   // build_cost block
static constexpr int   TPB     = 1024;  // main kernel block (16 waves)
static constexpr int   NWB     = TPB / 64;          // 16 waves/block
static constexpr int   NB      = 128;               // main grid blocks
static constexpr int   MAX_IT  = 100;
static constexpr float EPS     = 0.1f;
static constexpr float INV_EPS = 10.0f;
// logf(1/2048 + 1e-8)
static constexpr float LOG_AB  = -7.6245985063594f;
static constexpr float THRESH  = 0.1f;

#define ALOAD(p)     __hip_atomic_load((p),  __ATOMIC_RELAXED, __HIP_MEMORY_SCOPE_AGENT)
#define ASTORE(p, x) __hip_atomic_store((p), (x), __ATOMIC_RELAXED, __HIP_MEMORY_SCOPE_AGENT)

typedef unsigned long long u64;

// ---------------------------------------------------------------------------
// Cost matrix build + signal-region zeroing. C[i][j] = sum_d (x[i,d]-y[j,d])^2.
// (harness poisons ws with 0xAA before every call -> re-zero signals every
//  launch; kernel-end L2 writeback makes plain stores visible to bypass loads)
// ---------------------------------------------------------------------------
__global__ __launch_bounds__(TPB_B)
void build_cost(const float* __restrict__ x, const float* __restrict__ y,
                float* __restrict__ C, float* __restrict__ CT,
                unsigned* __restrict__ zz, int zcount,
                int c_aligned, int use_ct)
{
    __shared__ float xs[64][65];
    __shared__ float ys[64][65];
    const int t  = threadIdx.x;
    const int bi = blockIdx.y, bj = blockIdx.x;

    if (bi == 0) {                       // 32 blocks zero the region in parallel
        int per = (zcount + 31) / 32;
        int lo = bj * per;
        int hi = lo + per; if (hi > zcount) hi = zcount;
        for (int idx = lo + t; idx < hi; idx += TPB_B) zz[idx] = 0u;
    }

#pragma unroll
    for (int k = 0; k < 16; ++k) {
        int idx = t + TPB_B * k;
        int r = idx >> 6, c = idx & 63;
        xs[r][c] = x[(size_t)(bi * 64 + r) * 64 + c];
        ys[r][c] = y[(size_t)(bj * 64 + r) * 64 + c];
    }
    __syncthreads();

    const int ti0 = (t >> 4) * 4;
    const int tj0 = (t & 15) * 4;
    float acc[4][4] = {};
#pragma unroll 8
    for (int d = 0; d < 64; ++d) {
        float xv[4], yv[4];
#pragma unroll
        for (int k = 0; k < 4; ++k) xv[k] = xs[ti0 + k][d];
#pragma unroll
        for (int l = 0; l < 4; ++l) yv[l] = ys[tj0 + l][d];
#pragma unroll
        for (int k = 0; k < 4; ++k)
#pragma unroll
            for (int l = 0; l < 4; ++l) {
                float df = xv[k] - yv[l];
                acc[k][l] = fmaf(df, df, acc[k][l]);
            }
    }

#pragma unroll
    for (int k = 0; k < 4; ++k) {
        size_t off = (size_t)(bi * 64 + ti0 + k) * NN + bj * 64 + tj0;
        if (c_aligned) {
            *(float4*)(C + off) = make_float4(acc[k][0], acc[k][1], acc[k][2], acc[k][3]);
        } else {
            C[off + 0] = acc[k][0]; C[off + 1] = acc[k][1];
            C[off + 2] = acc[k][2]; C[off + 3] = acc[k][3];
        }
    }
    if (use_ct) {
#pragma unroll
        for (int l = 0; l < 4; ++l) {
            size_t off = (size_t)(bj * 64 + tj0 + l) * NN + bi * 64 + ti0;
            *(float4*)(CT + off) = make_float4(acc[0][l], acc[1][l], acc[2][l], acc[3][l]);
        }
    }
}

// ---------------------------------------------------------------------------
// Helpers
// ---------------------------------------------------------------------------
__device__ __forceinline__ void load_row32(const float* row, int lane,
                                           int aligned, float c[32])
{
    if (aligned) {
        const float4* r4 = (const float4*)row;
#pragma unroll
        for (int k = 0; k < 8; ++k) {
            float4 A = r4[lane + 64 * k];
            c[4*k+0] = A.x; c[4*k+1] = A.y; c[4*k+2] = A.z; c[4*k+3] = A.w;
        }
    } else {
#pragma unroll
        for (int k = 0; k < 8; ++k) {
            const float* p = row + 4 * (lane + 64 * k);
            c[4*k+0] = p[0]; c[4*k+1] = p[1]; c[4*k+2] = p[2]; c[4*k+3] = p[3];
        }
    }
}

__device__ __forceinline__ void lds_row32(const float* sv, int lane, float b[32])
{
    const float4* s4 = (const float4*)sv;
#pragma unroll
    for (int k = 0; k < 8; ++k) {
        float4 A = s4[lane + 64 * k];
        b[4*k+0] = A.x; b[4*k+1] = A.y; b[4*k+2] = A.z; b[4*k+3] = A.w;
    }
}

// wave-level lse of (b-c)*INV_EPS over 2048 elems; result on ALL lanes.
__device__ __forceinline__ float wave_lse(const float c[32], const float b[32])
{
    float M = b[0] - c[0];
#pragma unroll
    for (int k = 1; k < 32; ++k) M = fmaxf(M, b[k] - c[k]);
#pragma unroll
    for (int off = 1; off < 64; off <<= 1) M = fmaxf(M, __shfl_xor(M, off));
    float Ms = M * INV_EPS;
    float s = 0.0f;
#pragma unroll
    for (int k = 0; k < 32; ++k) s += __expf(fmaf(b[k] - c[k], INV_EPS, -Ms));
#pragma unroll
    for (int off = 1; off < 64; off <<= 1) s += __shfl_xor(s, off);
    return Ms + __logf(s);
}

// ---------------------------------------------------------------------------
// Main cooperative kernel — the proven 827us structure (R8), re-parameterized
// to NB=128 x TPB=1024 (16 waves/block, still 1 row/wave):
//   * poll transactions per round halve: 128 blocks x 128 lines = 16K
//     (transaction-bound round period ~0.2us instead of ~0.4us)
//   * barrier arrival population halves (128 posts)
//   * each thread polls 2 entries (2t, 2t+1) instead of 4
//   * 1024-thread launch bounds -> VGPR budget 128: crow/ccol fully resident
// Everything else is bit-identical in structure to the 827 kernel:
// self-validating {epoch|f32} u64 posts (staged, one coalesced wave-store),
// detection IS the data fetch, rot-deferred convergence check, no fences.
// Cm may alias out+1 (crow/ccol register-resident before any overwrite).
// ---------------------------------------------------------------------------
__global__ __launch_bounds__(TPB)
void sinkhorn_main(const float* Cm, const float* __restrict__ CT,
                   u64* __restrict__ valA, u64* __restrict__ valB,
                   u64* __restrict__ rotR, u64* __restrict__ rotC,
                   u64* __restrict__ costb,
                   float* out, int c_aligned, int use_ct)
{
    __shared__ float sv[2048];
    __shared__ float swave[NWB];
    __shared__ float sdw[NWB];
    __shared__ float sred4[4];
    __shared__ float sdiff;
    const int t = threadIdx.x, lane = t & 63, w = t >> 6, b = blockIdx.x;
    const int i = b * NWB + w;

    // loop-invariant C row / CT col -> registers
    float crow[32], ccol[32];
    load_row32(Cm + (size_t)i * NN, lane, c_aligned, crow);
    if (use_ct) {
        load_row32(CT + (size_t)i * NN, lane, 1, ccol);
    } else {
#pragma unroll
        for (int k = 0; k < 8; ++k)
#pragma unroll
            for (int kk = 0; kk < 4; ++kk)
                ccol[4*k+kk] = Cm[(size_t)(4 * (lane + 64 * k) + kk) * NN + i];
    }

    for (int k = t; k < 2048; k += TPB) sv[k] = 0.0f;   // v(0) = 0
    __syncthreads();

    float u_keep = 0.0f, v_keep = 0.0f;
    float b32[32];

    for (int it = 0; it < MAX_IT; ++it) {
        const unsigned ep = (unsigned)(it + 1);

        // ---- row compute: u(ep)_i from sv = v(it)
        lds_row32(sv, lane, b32);
        float lse   = wave_lse(crow, b32);
        float u_new = EPS * (LOG_AB - lse);          // wave-uniform
        float pdr   = fabsf(u_new - u_keep);

        // ---- deferred convergence check of iteration `it` (epoch it)
        if (it >= 1) {
            if (t < NB) {                            // 128 threads, 2 waves
                u64 r1, r2;
                const int ri = (it & 3) * NB + t;
                for (;;) { r1 = ALOAD(&rotR[ri]);
                           if ((unsigned)(r1 >> 32) >= (unsigned)it) break; }
                for (;;) { r2 = ALOAD(&rotC[ri]);
                           if ((unsigned)(r2 >> 32) >= (unsigned)it) break; }
                float d = __uint_as_float((unsigned)r1) +
                          __uint_as_float((unsigned)r2);
#pragma unroll
                for (int off = 1; off < 64; off <<= 1) d += __shfl_xor(d, off);
                if (lane == 0) sred4[w] = d;
            }
            __syncthreads();
            if (t == 0) sdiff = sred4[0] + sred4[1];
            __syncthreads();
            if (sdiff < THRESH) break;   // state: u_keep=u(it), v_keep, sv=v(it)
        }
        u_keep = u_new;

        // ---- post A(ep): staged values (one 128B wave-store) + block pdiff
        if (lane == 0) { swave[w] = u_new; sdw[w] = pdr; }
        __syncthreads();
        if (t < NWB)
            ASTORE(&valA[b * NWB + t],
                   ((u64)ep << 32) | __float_as_uint(swave[t]));
        if (t == 0) {
            float ps = 0.0f;
#pragma unroll
            for (int k = 0; k < NWB; ++k) ps += sdw[k];
            ASTORE(&rotR[(ep & 3) * NB + b],
                   ((u64)ep << 32) | __float_as_uint(ps));
        }
        // ---- poll A -> sv = u(ep)  (detection IS the fetch)
        {
            const int base = 2 * t;
            u64 d0, d1;
            for (;;) {
                d0 = ALOAD(&valA[base + 0]);
                d1 = ALOAD(&valA[base + 1]);
                if (((unsigned)(d0 >> 32) >= ep) & ((unsigned)(d1 >> 32) >= ep))
                    break;
            }
            ((float2*)sv)[t] = make_float2(__uint_as_float((unsigned)d0),
                                           __uint_as_float((unsigned)d1));
        }
        __syncthreads();

        // ---- col compute: v(ep)_j from sv = u(ep)
        lds_row32(sv, lane, b32);
        lse = wave_lse(ccol, b32);
        float v_new = EPS * (LOG_AB - lse);
        float pdc   = fabsf(v_new - v_keep);
        v_keep = v_new;

        if (lane == 0) { swave[w] = v_new; sdw[w] = pdc; }
        __syncthreads();
        if (t < NWB)
            ASTORE(&valB[b * NWB + t],
                   ((u64)ep << 32) | __float_as_uint(swave[t]));
        if (t == 0) {
            float ps = 0.0f;
#pragma unroll
            for (int k = 0; k < NWB; ++k) ps += sdw[k];
            ASTORE(&rotC[(ep & 3) * NB + b],
                   ((u64)ep << 32) | __float_as_uint(ps));
        }
        // ---- poll B -> sv = v(ep)
        {
            const int base = 2 * t;
            u64 d0, d1;
            for (;;) {
                d0 = ALOAD(&valB[base + 0]);
                d1 = ALOAD(&valB[base + 1]);
                if (((unsigned)(d0 >> 32) >= ep) & ((unsigned)(d1 >> 32) >= ep))
                    break;
            }
            ((float2*)sv)[t] = make_float2(__uint_as_float((unsigned)d0),
                                           __uint_as_float((unsigned)d1));
        }
        __syncthreads();
    }

    // ---- epilogue: pi = exp((u_i + v_j - C_ij)/eps), cost = sum(pi*C)
    float cpart = 0.0f;
    {
        lds_row32(sv, lane, b32);          // sv = final v
        const float ui = u_keep;           // own row's final u (wave-uniform)
        float* orow = out + 1 + (size_t)i * NN;
#pragma unroll
        for (int k = 0; k < 8; ++k) {
#pragma unroll
            for (int kk = 0; kk < 4; ++kk) {
                float cc = crow[4*k+kk];
                float p  = __expf((ui + b32[4*k+kk] - cc) * INV_EPS);
                cpart = fmaf(p, cc, cpart);
                orow[4 * (lane + 64 * k) + kk] = p;  // crow in regs: alias-safe
            }
        }
    }
#pragma unroll
    for (int off = 1; off < 64; off <<= 1) cpart += __shfl_xor(cpart, off);
    if (lane == 0) sdw[w] = cpart;
    __syncthreads();
    if (t == 0) {
        float pc = 0.0f;
#pragma unroll
        for (int k = 0; k < NWB; ++k) pc += sdw[k];
        ASTORE(&costb[b], (1ull << 32) | __float_as_uint(pc));
    }
    if (b == 0) {                          // block 0 gathers the cost total
        if (t < NB) {
            u64 h;
            for (;;) { h = ALOAD(&costb[t]); if (h >= (1ull << 32)) break; }
            float pc = __uint_as_float((unsigned)h);
#pragma unroll
            for (int off = 1; off < 64; off <<= 1) pc += __shfl_xor(pc, off);
            if (lane == 0) sred4[w] = pc;
        }
        __syncthreads();
        if (t == 0) out[0] = sred4[0] + sred4[1];
    }
}

// ---------------------------------------------------------------------------
extern "C" void kernel_launch(void* const* d_in, const int* in_sizes, int n_in,
                              void* d_out, int out_size, void* d_ws, size_t ws_size,
                              hipStream_t stream)
{
    (void)in_sizes; (void)n_in; (void)out_size;
    const float* x = (const float*)d_in[0];
    const float* y = (const float*)d_in[1];
    float* out = (float*)d_out;
    char*  ws  = (char*)d_ws;

    const size_t CB = (size_t)NN * NN * sizeof(float);   // 16 MiB
    // signals: valA(2048) valB(2048) rotR(4*128) rotC(4*128) costb(128) u64
    const int    ZU = 2048 + 2048 + 512 + 512 + 128;     // 5248 u64
    const size_t ZB = (size_t)ZU * sizeof(u64);

    float *Cm, *CT; char* zz;
    int c_aligned, use_ct;
    if (ws_size >= 2 * CB + ZB) {             // preferred: C, CT, signals in ws
        Cm = (float*)ws; CT = (float*)(ws + CB); zz = ws + 2 * CB;
        c_aligned = 1; use_ct = 1;
    } else if (ws_size >= CB + ZB) {          // C in out+1, CT in ws
        Cm = out + 1; CT = (float*)ws; zz = ws + CB;
        c_aligned = 0; use_ct = 1;
    } else {                                  // C in out+1, no CT (strided)
        Cm = out + 1; CT = nullptr; zz = ws;
        c_aligned = 0; use_ct = 0;
    }
    u64* valA  = (u64*)zz;
    u64* valB  = valA + 2048;
    u64* rotR  = valB + 2048;
    u64* rotC  = rotR + 512;
    u64* costb = rotC + 512;
    int  zcount = ZU * 2;                     // u32 elements to zero

    hipLaunchKernelGGL(build_cost, dim3(32, 32), dim3(TPB_B), 0, stream,
                       x, y, Cm, CT, (unsigned*)zz, zcount, c_aligned, use_ct);

    const float* Cmc = Cm;
    const float* CTc = CT;
    void* args[] = { (void*)&Cmc, (void*)&CTc, (void*)&valA, (void*)&valB,
                     (void*)&rotR, (void*)&rotC, (void*)&costb,
                     (void*)&out, (void*)&c_aligned, (void*)&use_ct };
    hipLaunchCooperativeKernel((void*)sinkhorn_main, dim3(NB), dim3(TPB),
                               args, 0, stream);
}